// Round 1
// baseline (131.784 us; speedup 1.0000x reference)
//
#include <hip/hip_runtime.h>
#include <math.h>

#define D 1024  // state dim, fixed by the problem

__device__ __forceinline__ float sigmoidf_(float v) {
    return 1.0f / (1.0f + expf(-v));
}

// Block-wide sum reduce; requires blockDim.x == 256 (4 waves of 64).
// Broadcasts result to all threads.
__device__ __forceinline__ float block_reduce_sum256(float v) {
    #pragma unroll
    for (int off = 32; off; off >>= 1) v += __shfl_down(v, off, 64);
    __shared__ float sm[4];
    int lane = threadIdx.x & 63, w = threadIdx.x >> 6;
    if (lane == 0) sm[w] = v;
    __syncthreads();
    return sm[0] + sm[1] + sm[2] + sm[3];
}

// tmp[row] = sum_k T[row,k] * W_T_2[k]   (T: 2048x2048, W_T_2: 2048)
__global__ void k_matvec_T(const float* __restrict__ T,
                           const float* __restrict__ w,
                           float* __restrict__ tmp) {
    int row = blockIdx.x;  // 2048 rows
    const float4* Tr = (const float4*)(T + (size_t)row * 2048);
    const float4* wv = (const float4*)w;
    float acc = 0.f;
    for (int i = threadIdx.x; i < 512; i += 256) {
        float4 a = Tr[i], b = wv[i];
        acc += a.x * b.x + a.y * b.y + a.z * b.z + a.w * b.w;
    }
    float s = block_reduce_sum256(acc);
    if (threadIdx.x == 0) tmp[row] = s;
}

// t_vec[row] = sigmoid( sum_k W_T_1[row,k]*tmp[k] + b_T[row] )   (W_T_1: 1024x2048)
__global__ void k_tvec(const float* __restrict__ W_T_1,
                       const float* __restrict__ tmp,
                       const float* __restrict__ b_T,
                       float* __restrict__ t_vec) {
    int row = blockIdx.x;  // 1024 rows
    const float4* Wr = (const float4*)(W_T_1 + (size_t)row * 2048);
    const float4* tv = (const float4*)tmp;
    float acc = 0.f;
    for (int i = threadIdx.x; i < 512; i += 256) {
        float4 a = Wr[i], b = tv[i];
        acc += a.x * b.x + a.y * b.y + a.z * b.z + a.w * b.w;
    }
    float s = block_reduce_sum256(acc);
    if (threadIdx.x == 0) t_vec[row] = sigmoidf_(s + b_T[row]);
}

// dots[0] = dot(x[POI], t_vec);  dots[1] = dot(s_u[user], t_vec)
__global__ void k_dots(const float* __restrict__ x,
                       const float* __restrict__ s_u,
                       const float* __restrict__ t_vec,
                       const int* __restrict__ user_ptr,
                       const int* __restrict__ POI_ptr,
                       float* __restrict__ dots) {
    const float* src = (blockIdx.x == 0)
        ? x + (size_t)POI_ptr[0] * D
        : s_u + (size_t)user_ptr[0] * D;
    const float4* a = (const float4*)src;
    const float4* b = (const float4*)t_vec;
    float acc = 0.f;
    // D/4 = 256 -> one float4 per thread
    float4 p = a[threadIdx.x], q = b[threadIdx.x];
    acc = p.x * q.x + p.y * q.y + p.z * q.z + p.w * q.w;
    float s = block_reduce_sum256(acc);
    if (threadIdx.x == 0) dots[blockIdx.x] = s;
}

// new_user[i] = sigmoid(s_u[user,i] + W_u[i]*dotP)
// new_POI[i]  = sigmoid(x[POI,i]   + W_p[i]*dotU)
__global__ void k_newrows(const float* __restrict__ s_u,
                          const float* __restrict__ x,
                          const float* __restrict__ W_u,
                          const float* __restrict__ W_p,
                          const int* __restrict__ user_ptr,
                          const int* __restrict__ POI_ptr,
                          const float* __restrict__ dots,
                          float* __restrict__ new_user,
                          float* __restrict__ new_POI) {
    int i = blockIdx.x * 256 + threadIdx.x;  // grid 4 x 256 = 1024
    int user = user_ptr[0], POI = POI_ptr[0];
    float dotP = dots[0], dotU = dots[1];
    new_user[i] = sigmoidf_(s_u[(size_t)user * D + i] + W_u[i] * dotP);
    new_POI[i]  = sigmoidf_(x[(size_t)POI * D + i] + W_p[i] * dotU);
}

// grid-stride float4 copy
__global__ void k_copy4(const float4* __restrict__ src,
                        float4* __restrict__ dst, int n4) {
    int i = blockIdx.x * blockDim.x + threadIdx.x;
    int stride = gridDim.x * blockDim.x;
    for (; i < n4; i += stride) dst[i] = src[i];
}

// overwrite updated rows
__global__ void k_fix(float* __restrict__ out_su, float* __restrict__ out_x,
                      const float* __restrict__ new_user,
                      const float* __restrict__ new_POI,
                      const int* __restrict__ user_ptr,
                      const int* __restrict__ POI_ptr) {
    int i = blockIdx.x * 256 + threadIdx.x;  // grid 4
    out_su[(size_t)user_ptr[0] * D + i] = new_user[i];
    out_x[(size_t)POI_ptr[0] * D + i] = new_POI[i];
}

// edges with head==POI: out_x[tail] = new_POI + edge_attr[e]; is_tail[tail]=1
__global__ void k_tail(const int* __restrict__ edge_index,
                       const float* __restrict__ edge_attr,
                       const float* __restrict__ new_POI,
                       const int* __restrict__ POI_ptr,
                       float* __restrict__ out_x,
                       int* __restrict__ is_tail, int E) {
    int e = blockIdx.x;
    if (edge_index[e] != POI_ptr[0]) return;   // heads
    int t = edge_index[E + e];                 // tails
    if (threadIdx.x == 0) is_tail[t] = 1;
    float4* dst = (float4*)(out_x + (size_t)t * D);
    const float4* ea = (const float4*)(edge_attr + (size_t)e * D);
    const float4* np = (const float4*)new_POI;
    float4 a = np[threadIdx.x], b = ea[threadIdx.x];
    dst[threadIdx.x] = make_float4(a.x + b.x, a.y + b.y, a.z + b.z, a.w + b.w);
}

// edges e != POI_index with is_tail[tails[e]]:
//   h = out_x[heads[e]]; scal = dot(h - edge_attr[e], W_p_);
//   out_x[heads[e]] = sigmoid(h + scal)
__global__ void k_neigh(const int* __restrict__ edge_index,
                        const float* __restrict__ edge_attr,
                        const float* __restrict__ Wp_row,
                        const int* __restrict__ is_tail,
                        const int* __restrict__ POI_ptr,
                        float* __restrict__ out_x, int E) {
    int e = blockIdx.x;
    if (e == POI_ptr[0]) return;               // neigh_mask .at[POI_index].set(False)
    int t = edge_index[E + e];
    if (!is_tail[t]) return;
    int h = edge_index[e];
    float4* xr = (float4*)(out_x + (size_t)h * D);
    const float4* ea = (const float4*)(edge_attr + (size_t)e * D);
    const float4* wv = (const float4*)Wp_row;
    float4 xv = xr[threadIdx.x];
    float4 ev = ea[threadIdx.x];
    float4 w = wv[threadIdx.x];
    float acc = (xv.x - ev.x) * w.x + (xv.y - ev.y) * w.y +
                (xv.z - ev.z) * w.z + (xv.w - ev.w) * w.w;
    float scal = block_reduce_sum256(acc);
    float4 o;
    o.x = sigmoidf_(xv.x + scal);
    o.y = sigmoidf_(xv.y + scal);
    o.z = sigmoidf_(xv.z + scal);
    o.w = sigmoidf_(xv.w + scal);
    xr[threadIdx.x] = o;
}

extern "C" void kernel_launch(void* const* d_in, const int* in_sizes, int n_in,
                              void* d_out, int out_size, void* d_ws, size_t ws_size,
                              hipStream_t stream) {
    const float* s_u       = (const float*)d_in[0];
    const float* x         = (const float*)d_in[1];
    const float* edge_attr = (const float*)d_in[2];
    const float* T         = (const float*)d_in[3];
    const float* W_u       = (const float*)d_in[4];
    const float* W_p       = (const float*)d_in[5];
    const float* W_T_1     = (const float*)d_in[6];
    const float* W_T_2     = (const float*)d_in[7];
    const float* b_T       = (const float*)d_in[8];
    const float* W_p_      = (const float*)d_in[9];
    const int*   edge_index = (const int*)d_in[10];
    const int*   user_ptr   = (const int*)d_in[11];
    const int*   POI_ptr    = (const int*)d_in[12];

    const int E       = in_sizes[10] / 2;   // 4096
    const int N_users = in_sizes[0] / D;    // 10000
    const int N       = in_sizes[1] / D;    // 50000

    float* out_su = (float*)d_out;
    float* out_x  = out_su + (size_t)N_users * D;

    float* ws_f     = (float*)d_ws;
    float* tmp      = ws_f;            // 2048
    float* t_vec    = ws_f + 2048;     // 1024
    float* dots     = ws_f + 3072;     // 2
    float* new_user = ws_f + 3584;     // 1024
    float* new_POI  = ws_f + 4608;     // 1024
    int*   is_tail  = (int*)(ws_f + 5632);  // N ints

    hipMemsetAsync(is_tail, 0, sizeof(int) * (size_t)N, stream);

    k_matvec_T<<<2048, 256, 0, stream>>>(T, W_T_2, tmp);
    k_tvec<<<1024, 256, 0, stream>>>(W_T_1, tmp, b_T, t_vec);
    k_dots<<<2, 256, 0, stream>>>(x, s_u, t_vec, user_ptr, POI_ptr, dots);
    k_newrows<<<4, 256, 0, stream>>>(s_u, x, W_u, W_p, user_ptr, POI_ptr, dots,
                                     new_user, new_POI);

    k_copy4<<<4096, 256, 0, stream>>>((const float4*)s_u, (float4*)out_su,
                                      (int)((size_t)N_users * D / 4));
    k_copy4<<<4096, 256, 0, stream>>>((const float4*)x, (float4*)out_x,
                                      (int)((size_t)N * D / 4));
    k_fix<<<4, 256, 0, stream>>>(out_su, out_x, new_user, new_POI,
                                 user_ptr, POI_ptr);
    k_tail<<<E, 256, 0, stream>>>(edge_index, edge_attr, new_POI, POI_ptr,
                                  out_x, is_tail, E);
    k_neigh<<<E, 256, 0, stream>>>(edge_index, edge_attr, W_p_, is_tail,
                                   POI_ptr, out_x, E);
}

// Round 2
// 125.509 us; speedup vs baseline: 1.0500x; 1.0500x over previous
//
#include <hip/hip_runtime.h>
#include <math.h>
#include <limits.h>

#define D 1024  // state dim, fixed by the problem

__device__ __forceinline__ float sigmoidf_(float v) {
    return 1.0f / (1.0f + expf(-v));
}

// Block-wide sum reduce for blockDim.x == 256 (4 waves). Broadcasts result.
// Safe for repeated calls (trailing barrier).
__device__ __forceinline__ float block_reduce_sum256(float v) {
    #pragma unroll
    for (int off = 32; off; off >>= 1) v += __shfl_down(v, off, 64);
    __shared__ float sm[4];
    int lane = threadIdx.x & 63, w = threadIdx.x >> 6;
    if (lane == 0) sm[w] = v;
    __syncthreads();
    float s = sm[0] + sm[1] + sm[2] + sm[3];
    __syncthreads();
    return s;
}

// Block-wide sum reduce for blockDim.x == 1024 (16 waves). Broadcasts result.
__device__ __forceinline__ float block_reduce_sum1024(float v) {
    #pragma unroll
    for (int off = 32; off; off >>= 1) v += __shfl_down(v, off, 64);
    __shared__ float sm[16];
    int lane = threadIdx.x & 63, w = threadIdx.x >> 6;
    if (lane == 0) sm[w] = v;
    __syncthreads();
    float s = 0.f;
    #pragma unroll
    for (int i = 0; i < 16; i++) s += sm[i];
    __syncthreads();
    return s;
}

// tmp[row] = sum_k T[row,k] * W_T_2[k]   (T: 2048x2048, W_T_2: 2048)
__global__ void k_matvec_T(const float* __restrict__ T,
                           const float* __restrict__ w,
                           float* __restrict__ tmp) {
    int row = blockIdx.x;  // 2048 rows
    const float4* Tr = (const float4*)(T + (size_t)row * 2048);
    const float4* wv = (const float4*)w;
    float acc = 0.f;
    for (int i = threadIdx.x; i < 512; i += 256) {
        float4 a = Tr[i], b = wv[i];
        acc += a.x * b.x + a.y * b.y + a.z * b.z + a.w * b.w;
    }
    float s = block_reduce_sum256(acc);
    if (threadIdx.x == 0) tmp[row] = s;
}

// t_vec[row] = sigmoid( sum_k W_T_1[row,k]*tmp[k] + b_T[row] )   (W_T_1: 1024x2048)
__global__ void k_tvec(const float* __restrict__ W_T_1,
                       const float* __restrict__ tmp,
                       const float* __restrict__ b_T,
                       float* __restrict__ t_vec) {
    int row = blockIdx.x;  // 1024 rows
    const float4* Wr = (const float4*)(W_T_1 + (size_t)row * 2048);
    const float4* tv = (const float4*)tmp;
    float acc = 0.f;
    for (int i = threadIdx.x; i < 512; i += 256) {
        float4 a = Wr[i], b = tv[i];
        acc += a.x * b.x + a.y * b.y + a.z * b.z + a.w * b.w;
    }
    float s = block_reduce_sum256(acc);
    if (threadIdx.x == 0) t_vec[row] = sigmoidf_(s + b_T[row]);
}

// Single block, 1024 threads.
// Phase 1: init tail_edge/neigh_edge entries for every row touched by any edge
//          (heads and tails) plus the POI row.
// Phase 2: tail_edge[tails[e]] = max e with heads[e]==POI  (np last-wins).
// Phase 3: neigh_edge[heads[e]] = max e with (e != POI_index && is_tail[tails[e]]).
// Phase 4: dots + new_user/new_POI rows.
__global__ void k_setup(const int* __restrict__ edge_index,
                        const float* __restrict__ x,
                        const float* __restrict__ s_u,
                        const float* __restrict__ t_vec,
                        const float* __restrict__ W_u,
                        const float* __restrict__ W_p,
                        const int* __restrict__ user_ptr,
                        const int* __restrict__ POI_ptr,
                        int* __restrict__ tail_edge,
                        int* __restrict__ neigh_edge,
                        float* __restrict__ new_user,
                        float* __restrict__ new_POI, int E) {
    const int tid = threadIdx.x;
    const int POI = POI_ptr[0], user = user_ptr[0];

    // phase 1: init every entry that will ever be read
    for (int e = tid; e < E; e += 1024) {
        int h = edge_index[e], t = edge_index[E + e];
        tail_edge[h] = -1;  tail_edge[t] = -1;
        neigh_edge[h] = -1; neigh_edge[t] = -1;
    }
    if (tid == 0) { tail_edge[POI] = -1; neigh_edge[POI] = -1; }
    __syncthreads();

    // phase 2: tail-scatter winners (atomics -> L2, coherent)
    for (int e = tid; e < E; e += 1024)
        if (edge_index[e] == POI) atomicMax(&tail_edge[edge_index[E + e]], e);
    __syncthreads();

    // phase 3: neigh-scatter winners. Read tail_edge through the atomic path
    // so we can't hit a stale L1 line from phase 1.
    for (int e = tid; e < E; e += 1024) {
        if (e == POI) continue;  // neigh_mask.at[POI_index].set(False)
        int t = edge_index[E + e];
        int te = atomicMax(&tail_edge[t], INT_MIN);  // read-only atomic
        if (te >= 0) atomicMax(&neigh_edge[edge_index[e]], e);
    }
    __syncthreads();

    // phase 4: dots on ORIGINAL rows, then the two updated rows
    float xv = x[(size_t)POI * D + tid];
    float uv = s_u[(size_t)user * D + tid];
    float tv = t_vec[tid];
    float dotP = block_reduce_sum1024(xv * tv);  // dot(x[POI], t_vec)
    float dotU = block_reduce_sum1024(uv * tv);  // dot(s_u[user], t_vec)
    new_user[tid] = sigmoidf_(uv + W_u[tid] * dotP);
    new_POI[tid]  = sigmoidf_(xv + W_p[tid] * dotU);
}

// One grid-stride float4 copy for the whole output (s_u then x regions).
__global__ void k_copy_all(const float4* __restrict__ su,
                           const float4* __restrict__ xx,
                           float4* __restrict__ out,
                           int n4_su, int n4_total) {
    int i = blockIdx.x * blockDim.x + threadIdx.x;
    int stride = gridDim.x * blockDim.x;
    for (; i < n4_total; i += stride)
        out[i] = (i < n4_su) ? su[i] : xx[i - n4_su];
}

// Grid: E+1 blocks x 256 threads. Deterministic single writer per output row:
//   neigh winner  > tail winner > POI/user special rows (skipped if overwritten).
__global__ void k_fixup(const int* __restrict__ edge_index,
                        const float* __restrict__ edge_attr,
                        const float* __restrict__ x,
                        const float* __restrict__ Wp_row,
                        const float* __restrict__ new_user,
                        const float* __restrict__ new_POI,
                        const int* __restrict__ tail_edge,
                        const int* __restrict__ neigh_edge,
                        const int* __restrict__ user_ptr,
                        const int* __restrict__ POI_ptr,
                        float* __restrict__ out_su,
                        float* __restrict__ out_x, int E) {
    const int e = blockIdx.x;
    const int tid = threadIdx.x;
    const int POI = POI_ptr[0];
    const float4* np_ = (const float4*)new_POI;

    if (e == E) {
        // user row always; POI row only if nothing later overwrites it
        int user = user_ptr[0];
        ((float4*)(out_su + (size_t)user * D))[tid] =
            ((const float4*)new_user)[tid];
        if (tail_edge[POI] < 0 && neigh_edge[POI] < 0)
            ((float4*)(out_x + (size_t)POI * D))[tid] = np_[tid];
        return;
    }

    const int h = edge_index[e], t = edge_index[E + e];

    // tail write: this edge is the last matched edge targeting row t, and no
    // neigh write will overwrite row t afterwards.
    if (h == POI && tail_edge[t] == e && neigh_edge[t] < 0) {
        const float4* ea = (const float4*)(edge_attr + (size_t)e * D);
        float4 a = np_[tid], b = ea[tid];
        ((float4*)(out_x + (size_t)t * D))[tid] =
            make_float4(a.x + b.x, a.y + b.y, a.z + b.z, a.w + b.w);
    }

    // neigh write: active edge and last one targeting row h.
    // Block-uniform condition -> the reductions below are barrier-safe.
    if (e != POI && tail_edge[t] >= 0 && neigh_edge[h] == e) {
        // base row = x state after POI-set and tail-scatter, before neigh
        float4 hv;
        int be = tail_edge[h];
        if (be >= 0) {
            const float4* eb = (const float4*)(edge_attr + (size_t)be * D);
            float4 a = np_[tid], b = eb[tid];
            hv = make_float4(a.x + b.x, a.y + b.y, a.z + b.z, a.w + b.w);
        } else if (h == POI) {
            hv = np_[tid];
        } else {
            hv = ((const float4*)(x + (size_t)h * D))[tid];
        }
        const float4* ea = (const float4*)(edge_attr + (size_t)e * D);
        float4 ev = ea[tid];
        float4 w = ((const float4*)Wp_row)[tid];
        float acc = (hv.x - ev.x) * w.x + (hv.y - ev.y) * w.y +
                    (hv.z - ev.z) * w.z + (hv.w - ev.w) * w.w;
        float scal = block_reduce_sum256(acc);
        float4 o;
        o.x = sigmoidf_(hv.x + scal);
        o.y = sigmoidf_(hv.y + scal);
        o.z = sigmoidf_(hv.z + scal);
        o.w = sigmoidf_(hv.w + scal);
        ((float4*)(out_x + (size_t)h * D))[tid] = o;
    }
}

extern "C" void kernel_launch(void* const* d_in, const int* in_sizes, int n_in,
                              void* d_out, int out_size, void* d_ws, size_t ws_size,
                              hipStream_t stream) {
    const float* s_u       = (const float*)d_in[0];
    const float* x         = (const float*)d_in[1];
    const float* edge_attr = (const float*)d_in[2];
    const float* T         = (const float*)d_in[3];
    const float* W_u       = (const float*)d_in[4];
    const float* W_p       = (const float*)d_in[5];
    const float* W_T_1     = (const float*)d_in[6];
    const float* W_T_2     = (const float*)d_in[7];
    const float* b_T       = (const float*)d_in[8];
    const float* W_p_      = (const float*)d_in[9];
    const int*   edge_index = (const int*)d_in[10];
    const int*   user_ptr   = (const int*)d_in[11];
    const int*   POI_ptr    = (const int*)d_in[12];

    const int E       = in_sizes[10] / 2;   // 4096
    const int N_users = in_sizes[0] / D;    // 10000
    const int N       = in_sizes[1] / D;    // 50000

    float* out_su = (float*)d_out;
    float* out_x  = out_su + (size_t)N_users * D;

    float* ws_f      = (float*)d_ws;
    float* tmp       = ws_f;                 // 2048
    float* t_vec     = ws_f + 2048;          // 1024
    float* new_user  = ws_f + 3072;          // 1024
    float* new_POI   = ws_f + 4096;          // 1024
    int*   tail_edge = (int*)(ws_f + 5120);  // N ints
    int*   neigh_edge = tail_edge + N;       // N ints

    k_matvec_T<<<2048, 256, 0, stream>>>(T, W_T_2, tmp);
    k_tvec<<<1024, 256, 0, stream>>>(W_T_1, tmp, b_T, t_vec);
    k_setup<<<1, 1024, 0, stream>>>(edge_index, x, s_u, t_vec, W_u, W_p,
                                    user_ptr, POI_ptr, tail_edge, neigh_edge,
                                    new_user, new_POI, E);

    const int n4_su = (int)((size_t)N_users * D / 4);
    const int n4_total = n4_su + (int)((size_t)N * D / 4);
    k_copy_all<<<4096, 256, 0, stream>>>((const float4*)s_u, (const float4*)x,
                                         (float4*)d_out, n4_su, n4_total);

    k_fixup<<<E + 1, 256, 0, stream>>>(edge_index, edge_attr, x, W_p_,
                                       new_user, new_POI, tail_edge, neigh_edge,
                                       user_ptr, POI_ptr, out_su, out_x, E);
}

// Round 3
// 113.108 us; speedup vs baseline: 1.1651x; 1.1096x over previous
//
#include <hip/hip_runtime.h>
#include <math.h>
#include <limits.h>

#define D 1024  // state dim, fixed by the problem

typedef float f32x4 __attribute__((ext_vector_type(4)));

__device__ __forceinline__ float sigmoidf_(float v) {
    return 1.0f / (1.0f + expf(-v));
}

// Block-wide sum reduce for blockDim.x == 256 (4 waves). Broadcasts result.
// Trailing barrier makes repeated calls safe.
__device__ __forceinline__ float block_reduce_sum256(float v) {
    #pragma unroll
    for (int off = 32; off; off >>= 1) v += __shfl_down(v, off, 64);
    __shared__ float sm[4];
    int lane = threadIdx.x & 63, w = threadIdx.x >> 6;
    if (lane == 0) sm[w] = v;
    __syncthreads();
    float s = sm[0] + sm[1] + sm[2] + sm[3];
    __syncthreads();
    return s;
}

// Blocks [0, n_rows): tmp[row] = sum_k T[row,k] * W_T_2[k]
// Block n_rows: edge classification (flags pre-initialized to -1 by memset):
//   tail_edge[t]  = max e with heads[e]==POI           (np .at[].set last-wins)
//   neigh_edge[h] = max e with e!=POI_index && tail_edge[tails[e]]>=0
__global__ void k_pre(const float* __restrict__ T,
                      const float* __restrict__ w,
                      float* __restrict__ tmp,
                      const int* __restrict__ edge_index,
                      const int* __restrict__ POI_ptr,
                      int* __restrict__ tail_edge,
                      int* __restrict__ neigh_edge,
                      int n_rows, int E, int t4 /* = N_T2/4 */) {
    const int b = blockIdx.x;
    const int tid = threadIdx.x;
    if (b < n_rows) {
        const float4* Tr = (const float4*)(T + (size_t)b * (size_t)(t4 * 4));
        const float4* wv = (const float4*)w;
        float acc = 0.f;
        for (int i = tid; i < t4; i += 256) {
            float4 a = Tr[i], c = wv[i];
            acc += a.x * c.x + a.y * c.y + a.z * c.z + a.w * c.w;
        }
        float s = block_reduce_sum256(acc);
        if (tid == 0) tmp[b] = s;
        return;
    }
    // classifier block
    const int POI = POI_ptr[0];
    for (int e = tid; e < E; e += 256)
        if (edge_index[e] == POI) atomicMax(&tail_edge[edge_index[E + e]], e);
    __syncthreads();
    for (int e = tid; e < E; e += 256) {
        if (e == POI) continue;  // neigh_mask.at[POI_index].set(False)
        // read through the atomic path (L2) so phase-2 results are visible
        int te = atomicMax(&tail_edge[edge_index[E + e]], INT_MIN);
        if (te >= 0) atomicMax(&neigh_edge[edge_index[e]], e);
    }
}

// t = sigmoid(W_T_1[row,:] @ tmp + b_T[row]); emit per-element dot products
// pu_P[row] = x[POI,row]*t  (for dotP = dot(x[POI], t_vec))
// pu_U[row] = s_u[user,row]*t (for dotU = dot(s_u[user], t_vec))
__global__ void k_tvec2(const float* __restrict__ W_T_1,
                        const float* __restrict__ tmp,
                        const float* __restrict__ b_T,
                        const float* __restrict__ x,
                        const float* __restrict__ s_u,
                        const int* __restrict__ user_ptr,
                        const int* __restrict__ POI_ptr,
                        float* __restrict__ pu_P,
                        float* __restrict__ pu_U,
                        int k4 /* = N_T1/4 */) {
    const int row = blockIdx.x;  // D rows
    const float4* Wr = (const float4*)(W_T_1 + (size_t)row * (size_t)(k4 * 4));
    const float4* tv = (const float4*)tmp;
    float acc = 0.f;
    for (int i = threadIdx.x; i < k4; i += 256) {
        float4 a = Wr[i], c = tv[i];
        acc += a.x * c.x + a.y * c.y + a.z * c.z + a.w * c.w;
    }
    float s = block_reduce_sum256(acc);
    if (threadIdx.x == 0) {
        float t = sigmoidf_(s + b_T[row]);
        pu_P[row] = x[(size_t)POI_ptr[0] * D + row] * t;
        pu_U[row] = s_u[(size_t)user_ptr[0] * D + row] * t;
    }
}

// One block per output row (N_users + N blocks, 256 threads, 1 float4/thread).
// Deterministic single writer per row:
//   s_u region: user row -> sigmoid(u + W_u*dotP); else stream copy.
//   x region:   neigh winner > tail winner > POI row > stream copy,
//   with the neigh base being the post-tail-scatter value (matches reference).
__global__ void k_mega(const float* __restrict__ s_u,
                       const float* __restrict__ x,
                       const float* __restrict__ edge_attr,
                       const float* __restrict__ W_u,
                       const float* __restrict__ W_p,
                       const float* __restrict__ Wp_row,
                       const int* __restrict__ user_ptr,
                       const int* __restrict__ POI_ptr,
                       const int* __restrict__ tail_edge,
                       const int* __restrict__ neigh_edge,
                       const float* __restrict__ pu_P,
                       const float* __restrict__ pu_U,
                       float* __restrict__ out,
                       int N_users, int E) {
    const int r = blockIdx.x;
    const int tid = threadIdx.x;

    if (r < N_users) {
        if (r == user_ptr[0]) {
            float4 pp = ((const float4*)pu_P)[tid];
            float dotP = block_reduce_sum256(pp.x + pp.y + pp.z + pp.w);
            float4 uv = ((const float4*)(s_u + (size_t)r * D))[tid];
            float4 wu = ((const float4*)W_u)[tid];
            float4 o;
            o.x = sigmoidf_(uv.x + wu.x * dotP);
            o.y = sigmoidf_(uv.y + wu.y * dotP);
            o.z = sigmoidf_(uv.z + wu.z * dotP);
            o.w = sigmoidf_(uv.w + wu.w * dotP);
            ((float4*)(out + (size_t)r * D))[tid] = o;
        } else {
            const f32x4* src = (const f32x4*)(s_u + (size_t)r * D);
            f32x4* dst = (f32x4*)(out + (size_t)r * D);
            f32x4 v = __builtin_nontemporal_load(&src[tid]);
            __builtin_nontemporal_store(v, &dst[tid]);
        }
        return;
    }

    const int j = r - N_users;
    const int ne = neigh_edge[j];
    const int te = tail_edge[j];
    const int POI = POI_ptr[0];

    if (ne < 0 && te < 0 && j != POI) {  // plain copy row
        const f32x4* src = (const f32x4*)(x + (size_t)j * D);
        f32x4* dst = (f32x4*)(out + (size_t)r * D);
        f32x4 v = __builtin_nontemporal_load(&src[tid]);
        __builtin_nontemporal_store(v, &dst[tid]);
        return;
    }

    // new_POI element: sigmoid(x[POI] + W_p*dotU), dotU = sum(pu_U)
    float4 uu = ((const float4*)pu_U)[tid];
    float dotU = block_reduce_sum256(uu.x + uu.y + uu.z + uu.w);
    float4 xp = ((const float4*)(x + (size_t)POI * D))[tid];
    float4 wp = ((const float4*)W_p)[tid];
    float4 np;
    np.x = sigmoidf_(xp.x + wp.x * dotU);
    np.y = sigmoidf_(xp.y + wp.y * dotU);
    np.z = sigmoidf_(xp.z + wp.z * dotU);
    np.w = sigmoidf_(xp.w + wp.w * dotU);

    // base value: x state after POI-set and tail-scatter
    float4 hv;
    if (te >= 0) {
        float4 b = ((const float4*)(edge_attr + (size_t)te * D))[tid];
        hv = make_float4(np.x + b.x, np.y + b.y, np.z + b.z, np.w + b.w);
    } else if (j == POI) {
        hv = np;
    } else {
        hv = ((const float4*)(x + (size_t)j * D))[tid];
    }

    float4* dst = (float4*)(out + (size_t)r * D);
    if (ne < 0) {  // tail winner or untouched POI row
        dst[tid] = hv;
        return;
    }

    // neigh winner: sigmoid(hv + dot(hv - edge_attr[ne], W_p_))
    float4 ev = ((const float4*)(edge_attr + (size_t)ne * D))[tid];
    float4 w = ((const float4*)Wp_row)[tid];
    float acc = (hv.x - ev.x) * w.x + (hv.y - ev.y) * w.y +
                (hv.z - ev.z) * w.z + (hv.w - ev.w) * w.w;
    float scal = block_reduce_sum256(acc);
    float4 o;
    o.x = sigmoidf_(hv.x + scal);
    o.y = sigmoidf_(hv.y + scal);
    o.z = sigmoidf_(hv.z + scal);
    o.w = sigmoidf_(hv.w + scal);
    dst[tid] = o;
}

extern "C" void kernel_launch(void* const* d_in, const int* in_sizes, int n_in,
                              void* d_out, int out_size, void* d_ws, size_t ws_size,
                              hipStream_t stream) {
    const float* s_u       = (const float*)d_in[0];
    const float* x         = (const float*)d_in[1];
    const float* edge_attr = (const float*)d_in[2];
    const float* T         = (const float*)d_in[3];
    const float* W_u       = (const float*)d_in[4];
    const float* W_p       = (const float*)d_in[5];
    const float* W_T_1     = (const float*)d_in[6];
    const float* W_T_2     = (const float*)d_in[7];
    const float* b_T       = (const float*)d_in[8];
    const float* W_p_      = (const float*)d_in[9];
    const int*   edge_index = (const int*)d_in[10];
    const int*   user_ptr   = (const int*)d_in[11];
    const int*   POI_ptr    = (const int*)d_in[12];

    const int E       = in_sizes[10] / 2;   // 4096
    const int N_users = in_sizes[0] / D;    // 10000
    const int N       = in_sizes[1] / D;    // 50000
    const int N_T2    = in_sizes[7];        // 2048 (rows of T @ W_T_2 inner dim)
    const int N_T1    = in_sizes[6] / D;    // 2048 (tmp length)

    float* ws_f       = (float*)d_ws;
    float* tmp        = ws_f;                       // N_T1
    float* pu_P       = ws_f + N_T1;                // D
    float* pu_U       = pu_P + D;                   // D
    int*   tail_edge  = (int*)(pu_U + D);           // N
    int*   neigh_edge = tail_edge + N;              // N

    // init both flag arrays to -1 (contiguous)
    hipMemsetAsync(tail_edge, 0xFF, sizeof(int) * (size_t)(2 * N), stream);

    k_pre<<<N_T1 + 1, 256, 0, stream>>>(T, W_T_2, tmp, edge_index, POI_ptr,
                                        tail_edge, neigh_edge, N_T1, E, N_T2 / 4);
    k_tvec2<<<D, 256, 0, stream>>>(W_T_1, tmp, b_T, x, s_u, user_ptr, POI_ptr,
                                   pu_P, pu_U, N_T1 / 4);
    k_mega<<<N_users + N, 256, 0, stream>>>(s_u, x, edge_attr, W_u, W_p, W_p_,
                                            user_ptr, POI_ptr, tail_edge,
                                            neigh_edge, pu_P, pu_U,
                                            (float*)d_out, N_users, E);
}

// Round 4
// 109.062 us; speedup vs baseline: 1.2083x; 1.0371x over previous
//
#include <hip/hip_runtime.h>
#include <math.h>
#include <limits.h>

#define D 1024  // state dim, fixed by the problem

typedef float f32x4 __attribute__((ext_vector_type(4)));

__device__ __forceinline__ float sigmoidf_(float v) {
    return 1.0f / (1.0f + expf(-v));
}

// Block-wide sum reduce for blockDim.x == 256 (4 waves). Broadcasts result.
// Trailing barrier makes repeated calls safe.
__device__ __forceinline__ float block_reduce_sum256(float v) {
    #pragma unroll
    for (int off = 32; off; off >>= 1) v += __shfl_down(v, off, 64);
    __shared__ float sm[4];
    int lane = threadIdx.x & 63, w = threadIdx.x >> 6;
    if (lane == 0) sm[w] = v;
    __syncthreads();
    float s = sm[0] + sm[1] + sm[2] + sm[3];
    __syncthreads();
    return s;
}

// Grid = N_T1 blocks. Every block: grid-stride init of the flag arrays to -1
// (2N ints, <=1 store per thread). Then tmp[row] = T[row,:] @ W_T_2.
__global__ void k_pre(const float* __restrict__ T,
                      const float* __restrict__ w,
                      float* __restrict__ tmp,
                      int* __restrict__ flags,   // tail_edge ++ neigh_edge
                      int n_flags, int t4 /* = N_T2/4 */) {
    const int tid = threadIdx.x;
    int gid = blockIdx.x * 256 + tid;
    int gsz = gridDim.x * 256;
    for (int i = gid; i < n_flags; i += gsz) flags[i] = -1;

    const int row = blockIdx.x;
    const float4* Tr = (const float4*)(T + (size_t)row * (size_t)(t4 * 4));
    const float4* wv = (const float4*)w;
    float acc = 0.f;
    for (int i = tid; i < t4; i += 256) {
        float4 a = Tr[i], c = wv[i];
        acc += a.x * c.x + a.y * c.y + a.z * c.z + a.w * c.w;
    }
    float s = block_reduce_sum256(acc);
    if (tid == 0) tmp[row] = s;
}

// Grid = D+1 blocks.
// Blocks [0,D): t = sigmoid(W_T_1[row,:] @ tmp + b_T[row]);
//   pu_P[row] = x[POI,row]*t ; pu_U[row] = s_u[user,row]*t.
// Block D: edge classification on the pre-initialized flags:
//   tail_edge[t]  = max e with heads[e]==POI              (np last-wins)
//   neigh_edge[h] = max e with e!=POI_index && tail_edge[tails[e]]>=0
__global__ void k_tvec2(const float* __restrict__ W_T_1,
                        const float* __restrict__ tmp,
                        const float* __restrict__ b_T,
                        const float* __restrict__ x,
                        const float* __restrict__ s_u,
                        const int* __restrict__ user_ptr,
                        const int* __restrict__ POI_ptr,
                        const int* __restrict__ edge_index,
                        int* __restrict__ tail_edge,
                        int* __restrict__ neigh_edge,
                        float* __restrict__ pu_P,
                        float* __restrict__ pu_U,
                        int k4 /* = N_T1/4 */, int E) {
    const int tid = threadIdx.x;
    if (blockIdx.x == gridDim.x - 1) {  // classifier block
        const int POI = POI_ptr[0];
        for (int e = tid; e < E; e += 256)
            if (edge_index[e] == POI)
                atomicMax(&tail_edge[edge_index[E + e]], e);
        __syncthreads();
        for (int e = tid; e < E; e += 256) {
            if (e == POI) continue;  // neigh_mask.at[POI_index].set(False)
            // read via atomic path (L2) so phase-1 results are visible
            int te = atomicMax(&tail_edge[edge_index[E + e]], INT_MIN);
            if (te >= 0) atomicMax(&neigh_edge[edge_index[e]], e);
        }
        return;
    }
    const int row = blockIdx.x;  // D rows
    const float4* Wr = (const float4*)(W_T_1 + (size_t)row * (size_t)(k4 * 4));
    const float4* tv = (const float4*)tmp;
    float acc = 0.f;
    for (int i = tid; i < k4; i += 256) {
        float4 a = Wr[i], c = tv[i];
        acc += a.x * c.x + a.y * c.y + a.z * c.z + a.w * c.w;
    }
    float s = block_reduce_sum256(acc);
    if (tid == 0) {
        float t = sigmoidf_(s + b_T[row]);
        pu_P[row] = x[(size_t)POI_ptr[0] * D + row] * t;
        pu_U[row] = s_u[(size_t)user_ptr[0] * D + row] * t;
    }
}

// Grid = ceil((N_users+N)/8) blocks x 256 threads; 8 rows per block, each
// thread owns one float4 slot of all 8 rows (speculative loads -> 8x MLP).
// Deterministic single writer per row:
//   s_u region: user row -> sigmoid(u + W_u*dotP); else stream copy.
//   x region:   neigh winner > tail winner > POI row > stream copy,
//   neigh base = post-tail-scatter value (matches reference order).
// All branches are block-uniform, so the barrier-based reductions are safe.
__global__ void k_mega8(const float* __restrict__ s_u,
                        const float* __restrict__ x,
                        const float* __restrict__ edge_attr,
                        const float* __restrict__ W_u,
                        const float* __restrict__ W_p,
                        const float* __restrict__ Wp_row,
                        const int* __restrict__ user_ptr,
                        const int* __restrict__ POI_ptr,
                        const int* __restrict__ tail_edge,
                        const int* __restrict__ neigh_edge,
                        const float* __restrict__ pu_P,
                        const float* __restrict__ pu_U,
                        float* __restrict__ out,
                        int N_users, int total_rows) {
    const int tid = threadIdx.x;
    const int base = blockIdx.x * 8;
    const int user = user_ptr[0], POI = POI_ptr[0];

    // speculative row loads (used by copy path, user path, and neigh-base)
    f32x4 v[8];
    #pragma unroll
    for (int k = 0; k < 8; k++) {
        int r = base + k;
        if (r >= total_rows) continue;
        const float* src = (r < N_users) ? s_u + (size_t)r * D
                                         : x + (size_t)(r - N_users) * D;
        v[k] = __builtin_nontemporal_load((const f32x4*)src + tid);
    }

    int te[8], ne[8];
    bool sp[8];
    #pragma unroll
    for (int k = 0; k < 8; k++) {
        int r = base + k;
        te[k] = -1; ne[k] = -1; sp[k] = false;
        if (r >= total_rows) continue;
        if (r < N_users) {
            sp[k] = (r == user);
        } else {
            int j = r - N_users;
            te[k] = tail_edge[j];
            ne[k] = neigh_edge[j];
            sp[k] = (te[k] >= 0) || (ne[k] >= 0) || (j == POI);
        }
    }

    #pragma unroll
    for (int k = 0; k < 8; k++) {
        int r = base + k;
        if (r >= total_rows) continue;
        f32x4* dst = (f32x4*)(out + (size_t)r * D) + tid;
        if (!sp[k]) {  // plain stream copy
            __builtin_nontemporal_store(v[k], dst);
            continue;
        }
        if (r < N_users) {  // user row
            f32x4 pp = ((const f32x4*)pu_P)[tid];
            float dotP = block_reduce_sum256(pp.x + pp.y + pp.z + pp.w);
            f32x4 wu = ((const f32x4*)W_u)[tid];
            f32x4 o;
            o.x = sigmoidf_(v[k].x + wu.x * dotP);
            o.y = sigmoidf_(v[k].y + wu.y * dotP);
            o.z = sigmoidf_(v[k].z + wu.z * dotP);
            o.w = sigmoidf_(v[k].w + wu.w * dotP);
            __builtin_nontemporal_store(o, dst);
            continue;
        }
        const int j = r - N_users;
        // new_POI element: sigmoid(x[POI] + W_p * dotU)
        f32x4 uu = ((const f32x4*)pu_U)[tid];
        float dotU = block_reduce_sum256(uu.x + uu.y + uu.z + uu.w);
        f32x4 xp = ((const f32x4*)(x + (size_t)POI * D))[tid];
        f32x4 wp = ((const f32x4*)W_p)[tid];
        f32x4 np;
        np.x = sigmoidf_(xp.x + wp.x * dotU);
        np.y = sigmoidf_(xp.y + wp.y * dotU);
        np.z = sigmoidf_(xp.z + wp.z * dotU);
        np.w = sigmoidf_(xp.w + wp.w * dotU);
        // base value: x state after POI-set and tail-scatter
        f32x4 hv;
        if (te[k] >= 0) {
            f32x4 b = ((const f32x4*)(edge_attr + (size_t)te[k] * D))[tid];
            hv = np + b;
        } else if (j == POI) {
            hv = np;
        } else {
            hv = v[k];
        }
        if (ne[k] < 0) {  // tail winner or untouched POI row
            __builtin_nontemporal_store(hv, dst);
            continue;
        }
        // neigh winner: sigmoid(hv + dot(hv - edge_attr[ne], W_p_))
        f32x4 ev = ((const f32x4*)(edge_attr + (size_t)ne[k] * D))[tid];
        f32x4 w = ((const f32x4*)Wp_row)[tid];
        f32x4 dd = hv - ev;
        float acc = dd.x * w.x + dd.y * w.y + dd.z * w.z + dd.w * w.w;
        float scal = block_reduce_sum256(acc);
        f32x4 o;
        o.x = sigmoidf_(hv.x + scal);
        o.y = sigmoidf_(hv.y + scal);
        o.z = sigmoidf_(hv.z + scal);
        o.w = sigmoidf_(hv.w + scal);
        __builtin_nontemporal_store(o, dst);
    }
}

extern "C" void kernel_launch(void* const* d_in, const int* in_sizes, int n_in,
                              void* d_out, int out_size, void* d_ws, size_t ws_size,
                              hipStream_t stream) {
    const float* s_u       = (const float*)d_in[0];
    const float* x         = (const float*)d_in[1];
    const float* edge_attr = (const float*)d_in[2];
    const float* T         = (const float*)d_in[3];
    const float* W_u       = (const float*)d_in[4];
    const float* W_p       = (const float*)d_in[5];
    const float* W_T_1     = (const float*)d_in[6];
    const float* W_T_2     = (const float*)d_in[7];
    const float* b_T       = (const float*)d_in[8];
    const float* W_p_      = (const float*)d_in[9];
    const int*   edge_index = (const int*)d_in[10];
    const int*   user_ptr   = (const int*)d_in[11];
    const int*   POI_ptr    = (const int*)d_in[12];

    const int E       = in_sizes[10] / 2;   // 4096
    const int N_users = in_sizes[0] / D;    // 10000
    const int N       = in_sizes[1] / D;    // 50000
    const int N_T2    = in_sizes[7];        // 2048
    const int N_T1    = in_sizes[6] / D;    // 2048

    float* ws_f       = (float*)d_ws;
    float* tmp        = ws_f;                       // N_T1
    float* pu_P       = ws_f + N_T1;                // D
    float* pu_U       = pu_P + D;                   // D
    int*   tail_edge  = (int*)(pu_U + D);           // N
    int*   neigh_edge = tail_edge + N;              // N (contiguous with tail)

    // 1) flag init (grid-stride) + tmp = T @ W_T_2
    k_pre<<<N_T1, 256, 0, stream>>>(T, W_T_2, tmp, tail_edge, 2 * N, N_T2 / 4);

    // 2) t_vec rows (+ per-element dot products) + edge classifier block
    k_tvec2<<<D + 1, 256, 0, stream>>>(W_T_1, tmp, b_T, x, s_u, user_ptr,
                                       POI_ptr, edge_index, tail_edge,
                                       neigh_edge, pu_P, pu_U, N_T1 / 4, E);

    // 3) fused copy + all row updates, 8 rows per block
    const int total_rows = N_users + N;
    k_mega8<<<(total_rows + 7) / 8, 256, 0, stream>>>(
        s_u, x, edge_attr, W_u, W_p, W_p_, user_ptr, POI_ptr,
        tail_edge, neigh_edge, pu_P, pu_U, (float*)d_out, N_users, total_rows);
}